// Round 11
// baseline (176.743 us; speedup 1.0000x reference)
//
#include <hip/hip_runtime.h>

#define N_NODES 50000
#define N_EDGES 800000
#define D 128

#define NBLK 256                  // partition blocks (barrier participants)
#define EPB (N_EDGES / NBLK)      // 3125 edges per partition block
#define NBKT 196                  // coarse buckets of 256 nodes

typedef __attribute__((ext_vector_type(8))) short bf16x8;
typedef __attribute__((ext_vector_type(4))) float f32x4;

// ---------------- workspace layout (bytes) ----------------
static const size_t OFF_BAR  = 0;          // int[4] grid-barrier counters (zeroed)
static const size_t OFF_BASE = 256;        // int[196] bucket base (edge index)
static const size_t OFF_TOT  = 1280;       // int[196] bucket edge count
static const size_t OFF_WT   = 2304;       // ushort[128*128] bf16 W^T [n][k]
static const size_t OFF_H    = 35072;      // int[196*256] per-(bucket,block) counts
static const size_t OFF_BB   = 235776;     // int[196*256] rel scatter bases
static const size_t OFF_DEG  = 436480;     // int[50000]
static const size_t OFF_OFFS = 636480;     // int[50000]
static const size_t OFF_INV  = 836480;     // float[50000]
static const size_t OFF_REC  = 1036480;    // uint[800000] (src | dstLocal<<16)
static const size_t OFF_CSR  = 4236480;    // ushort[800000]
static const size_t OFF_XWB  = 5836480;    // ushort[50000*128] bf16
// total: 18,636,480 bytes

#define BM 64
#define NB_GEMM ((N_NODES + BM - 1) / BM)   // 782

__device__ __forceinline__ unsigned short f2bf(float f) {
    unsigned int u = __float_as_uint(f);
    unsigned int r = (u + 0x7fffu + ((u >> 16) & 1u)) >> 16;   // RNE
    return (unsigned short)r;
}
__device__ __forceinline__ float bflo(unsigned int u) { return __uint_as_float(u << 16); }
__device__ __forceinline__ float bfhi(unsigned int u) { return __uint_as_float(u & 0xffff0000u); }

// grid barrier over the NBLK partition blocks only
__device__ __forceinline__ void gsync(int* __restrict__ bar, int idx) {
    __syncthreads();
    if (threadIdx.x == 0) {
        __threadfence();
        atomicAdd(&bar[idx], 1);
        while (atomicAdd(&bar[idx], 0) < NBLK) __builtin_amdgcn_s_sleep(2);
        __threadfence();
    }
    __syncthreads();
}

// ---- init: zero barrier counters, convert Wt[n][k] = bf16(W[k][n]) ----
__global__ void k_init(int* __restrict__ bar, const float* __restrict__ W,
                       unsigned short* __restrict__ Wt) {
    int bid = blockIdx.x, t = threadIdx.x;
    if (bid == 0) {
        if (t < 4) bar[t] = 0;
    } else {
        int idx = (bid - 1) * 256 + t;   // 0..16383
        int n = idx >> 7, k = idx & 127;
        Wt[n * D + k] = f2bf(W[k * D + n]);
    }
}

// ---- fused: partition (blocks 0..255, barrier-synced) + GEMM (blocks 256..1037) ----
__global__ __launch_bounds__(256) void k_main(const float* __restrict__ X,
                                              const unsigned short* __restrict__ Wt,
                                              unsigned short* __restrict__ XWb,
                                              const int* __restrict__ src,
                                              const int* __restrict__ dst,
                                              int* __restrict__ H,
                                              int* __restrict__ BB,
                                              int* __restrict__ TOT,
                                              int* __restrict__ BASE,
                                              int* __restrict__ bar,
                                              int* __restrict__ deg,
                                              int* __restrict__ offs,
                                              float* __restrict__ inv,
                                              unsigned int* __restrict__ rec,
                                              unsigned short* __restrict__ csr) {
    __shared__ unsigned short sA[BM * D];    // 16KB (gemm A) / partition scratch
    __shared__ unsigned short sB[D * D];     // 32KB (gemm B) / partition scratch
    __shared__ int wtot[4], woff[4];
    int bid = blockIdx.x;
    int t = threadIdx.x;

    if (bid >= NBLK) {
        // ---------------- GEMM path ----------------
        int r0 = (bid - NBLK) * BM;

        #pragma unroll
        for (int p = 0; p < 8; ++p) {
            int e = p * 2048 + t * 8;
            int n = e >> 7, k = e & 127;
            uint4 v = *(const uint4*)&Wt[e];
            int idx = n * D + (((k >> 3) ^ (n & 7)) << 3);
            *(uint4*)&sB[idx] = v;
        }
        #pragma unroll
        for (int p = 0; p < 8; ++p) {
            int e = p * 1024 + t * 4;
            int r = e >> 7, c = e & 127;
            int row = r0 + r;
            float4 xv = make_float4(0.f, 0.f, 0.f, 0.f);
            if (row < N_NODES) xv = *(const float4*)&X[row * D + c];
            ushort4 bv;
            bv.x = f2bf(xv.x); bv.y = f2bf(xv.y); bv.z = f2bf(xv.z); bv.w = f2bf(xv.w);
            int idx = r * D + (((c >> 3) ^ (r & 7)) << 3) + (c & 7);
            *(ushort4*)&sA[idx] = bv;
        }
        __syncthreads();

        int w = t >> 6, l = t & 63;
        int arow = w * 16 + (l & 15);
        f32x4 acc[8];
        #pragma unroll
        for (int i = 0; i < 8; ++i) acc[i] = (f32x4){0.f, 0.f, 0.f, 0.f};

        #pragma unroll
        for (int kk = 0; kk < 4; ++kk) {
            int g = kk * 4 + (l >> 4);
            bf16x8 a = *(bf16x8*)&sA[arow * D + ((g ^ (arow & 7)) << 3)];
            #pragma unroll
            for (int nt = 0; nt < 8; ++nt) {
                int nrow = nt * 16 + (l & 15);
                bf16x8 b = *(bf16x8*)&sB[nrow * D + ((g ^ (nrow & 7)) << 3)];
                acc[nt] = __builtin_amdgcn_mfma_f32_16x16x32_bf16(a, b, acc[nt], 0, 0, 0);
            }
        }

        #pragma unroll
        for (int nt = 0; nt < 8; ++nt) {
            #pragma unroll
            for (int r = 0; r < 4; ++r) {
                int m = r0 + w * 16 + (l >> 4) * 4 + r;
                if (m < N_NODES) XWb[m * D + nt * 16 + (l & 15)] = f2bf(acc[nt][r]);
            }
        }
        return;
    }

    // ---------------- partition path ----------------
    unsigned int* lcnt = (unsigned int*)sA;       // [256]
    int* off_l = ((int*)sA) + 256;                // [256]
    int* lBB = (int*)sB;                          // [196]
    int b = bid;
    int e0 = b * EPB;
    int w = t >> 6, l = t & 63;

    // phase A: coarse histogram
    lcnt[t] = 0;
    __syncthreads();
    for (int i = t; i < EPB; i += 256)
        atomicAdd(&lcnt[dst[e0 + i] >> 8], 1u);
    __syncthreads();
    if (t < NBKT) H[t * NBLK + b] = (int)lcnt[t];
    gsync(bar, 0);

    // phase B: per-bucket scan over blocks (blocks 0..195)
    if (b < NBKT) {
        int v = H[b * NBLK + t];
        int s = v;
        #pragma unroll
        for (int d = 1; d < 64; d <<= 1) {
            int u = __shfl_up(s, d, 64);
            if (l >= d) s += u;
        }
        if (l == 63) wtot[w] = s;
        __syncthreads();
        if (t == 0) {
            woff[0] = 0; woff[1] = wtot[0];
            woff[2] = wtot[0] + wtot[1]; woff[3] = wtot[0] + wtot[1] + wtot[2];
        }
        __syncthreads();
        int excl = s - v + woff[w];
        BB[b * NBLK + t] = excl;
        if (t == 255) TOT[b] = excl + v;
    }
    gsync(bar, 1);

    // phase B2: block 0 scans bucket totals -> BASE
    if (b == 0) {
        int v = (t < NBKT) ? TOT[t] : 0;
        int s = v;
        #pragma unroll
        for (int d = 1; d < 64; d <<= 1) {
            int u = __shfl_up(s, d, 64);
            if (l >= d) s += u;
        }
        if (l == 63) wtot[w] = s;
        __syncthreads();
        if (t == 0) {
            woff[0] = 0; woff[1] = wtot[0];
            woff[2] = wtot[0] + wtot[1]; woff[3] = wtot[0] + wtot[1] + wtot[2];
        }
        __syncthreads();
        if (t < NBKT) BASE[t] = s - v + woff[w];
    }
    gsync(bar, 2);

    // phase C: rank-capturing scatter of records (bucket-grouped)
    lcnt[t] = 0;
    __syncthreads();
    if (t < NBKT) lBB[t] = BASE[t] + BB[t * NBLK + b];
    __syncthreads();
    for (int i = t; i < EPB; i += 256) {
        int e = e0 + i;
        int d = dst[e];
        int k = d >> 8;
        unsigned int r = atomicAdd(&lcnt[k], 1u);
        rec[lBB[k] + (int)r] = (unsigned int)src[e] | ((unsigned int)(d & 255) << 16);
    }
    gsync(bar, 3);

    // phase D: exact-dst sort within bucket (blocks 0..195)
    if (b < NBKT) {
        int base = BASE[b], tot = TOT[b];
        lcnt[t] = 0;
        __syncthreads();
        for (int i = t; i < tot; i += 256)
            atomicAdd(&lcnt[rec[base + i] >> 16], 1u);
        __syncthreads();

        int v = (int)lcnt[t];
        int s = v;
        #pragma unroll
        for (int d = 1; d < 64; d <<= 1) {
            int u = __shfl_up(s, d, 64);
            if (l >= d) s += u;
        }
        if (l == 63) wtot[w] = s;
        __syncthreads();
        if (t == 0) {
            woff[0] = 0; woff[1] = wtot[0];
            woff[2] = wtot[0] + wtot[1]; woff[3] = wtot[0] + wtot[1] + wtot[2];
        }
        __syncthreads();
        int excl = s - v + woff[w];
        off_l[t] = excl;
        int node = b * 256 + t;
        if (node < N_NODES) {
            deg[node] = v;
            inv[node] = rsqrtf((float)v + 1.0f);
            offs[node] = base + excl;
        }
        __syncthreads();
        lcnt[t] = 0;
        __syncthreads();
        for (int i = t; i < tot; i += 256) {
            unsigned int rc = rec[base + i];
            int dl = rc >> 16;
            unsigned int r = atomicAdd(&lcnt[dl], 1u);
            csr[base + off_l[dl] + (int)r] = (unsigned short)(rc & 0xFFFFu);
        }
    }
}

// ---- aggregate (bf16 gather, f32 out), 4-deep gather pipeline ----
__global__ __launch_bounds__(256) void k_agg(const unsigned short* __restrict__ XWb,
                                             const unsigned short* __restrict__ csr,
                                             const int* __restrict__ offs,
                                             const int* __restrict__ deg,
                                             const float* __restrict__ inv,
                                             float* __restrict__ out) {
    int node = blockIdx.x * 4 + (threadIdx.x >> 6);
    if (node >= N_NODES) return;
    int l = threadIdx.x & 63;
    int eg = l >> 4;
    int cl = l & 15;

    int start = offs[node];
    int cnt = deg[node];
    float invd = inv[node];

    float acc[8];
    #pragma unroll
    for (int j = 0; j < 8; ++j) acc[j] = 0.f;

    if (eg == 0) {
        float sl = invd * invd;
        uint4 v = *(const uint4*)&XWb[node * D + cl * 8];
        acc[0] += sl * bflo(v.x); acc[1] += sl * bfhi(v.x);
        acc[2] += sl * bflo(v.y); acc[3] += sl * bfhi(v.y);
        acc[4] += sl * bflo(v.z); acc[5] += sl * bfhi(v.z);
        acc[6] += sl * bflo(v.w); acc[7] += sl * bfhi(v.w);
    }

    for (int e = eg; e < cnt; e += 16) {
        int s[4];
        #pragma unroll
        for (int u = 0; u < 4; ++u) {
            int ee = e + u * 4;
            s[u] = (ee < cnt) ? (int)csr[start + ee] : -1;
        }
        uint4 v[4];
        float nn[4];
        #pragma unroll
        for (int u = 0; u < 4; ++u) {
            int si = (s[u] >= 0) ? s[u] : s[0];
            v[u] = *(const uint4*)&XWb[si * D + cl * 8];
            nn[u] = (s[u] >= 0) ? invd * inv[si] : 0.f;
        }
        #pragma unroll
        for (int u = 0; u < 4; ++u) {
            float n = nn[u];
            acc[0] += n * bflo(v[u].x); acc[1] += n * bfhi(v[u].x);
            acc[2] += n * bflo(v[u].y); acc[3] += n * bfhi(v[u].y);
            acc[4] += n * bflo(v[u].z); acc[5] += n * bfhi(v[u].z);
            acc[6] += n * bflo(v[u].w); acc[7] += n * bfhi(v[u].w);
        }
    }

    #pragma unroll
    for (int j = 0; j < 8; ++j) {
        acc[j] += __shfl_xor(acc[j], 16, 64);
        acc[j] += __shfl_xor(acc[j], 32, 64);
    }

    if (l < 16) {
        float4 v0 = make_float4(acc[0], acc[1], acc[2], acc[3]);
        float4 v1 = make_float4(acc[4], acc[5], acc[6], acc[7]);
        *(float4*)&out[node * D + cl * 8] = v0;
        *(float4*)&out[node * D + cl * 8 + 4] = v1;
    }
}

extern "C" void kernel_launch(void* const* d_in, const int* in_sizes, int n_in,
                              void* d_out, int out_size, void* d_ws, size_t ws_size,
                              hipStream_t stream) {
    const float* X = (const float*)d_in[0];
    const float* W = (const float*)d_in[1];
    const int* esrc = (const int*)d_in[2];
    const int* edst = (const int*)d_in[3];
    float* out = (float*)d_out;

    char* ws = (char*)d_ws;
    int* bar = (int*)(ws + OFF_BAR);
    int* BASE = (int*)(ws + OFF_BASE);
    int* TOT = (int*)(ws + OFF_TOT);
    unsigned short* Wt = (unsigned short*)(ws + OFF_WT);
    int* H = (int*)(ws + OFF_H);
    int* BB = (int*)(ws + OFF_BB);
    int* deg = (int*)(ws + OFF_DEG);
    int* offs = (int*)(ws + OFF_OFFS);
    float* inv = (float*)(ws + OFF_INV);
    unsigned int* rec = (unsigned int*)(ws + OFF_REC);
    unsigned short* csr = (unsigned short*)(ws + OFF_CSR);
    unsigned short* XWb = (unsigned short*)(ws + OFF_XWB);

    k_init<<<65, 256, 0, stream>>>(bar, W, Wt);
    k_main<<<NBLK + NB_GEMM, 256, 0, stream>>>(X, Wt, XWb, esrc, edst,
                                               H, BB, TOT, BASE, bar,
                                               deg, offs, inv, rec, csr);
    k_agg<<<(N_NODES + 3) / 4, 256, 0, stream>>>(XWb, csr, offs, deg, inv, out);
}

// Round 12
// 87.359 us; speedup vs baseline: 2.0232x; 2.0232x over previous
//
#include <hip/hip_runtime.h>

#define N_NODES 50000
#define N_EDGES 800000
#define D 128

#define NBLK 256                  // partition blocks
#define EPB (N_EDGES / NBLK)      // 3125 edges per block
#define NBKT 196                  // coarse buckets of 256 nodes

typedef __attribute__((ext_vector_type(8))) short bf16x8;
typedef __attribute__((ext_vector_type(4))) float f32x4;

// ---------------- workspace layout (bytes) ----------------
static const size_t OFF_FLAG = 0;          // int[196] lookback flags (zeroed by k_pre)
static const size_t OFF_BASE = 1024;       // int[196] bucket base (edge index)
static const size_t OFF_TOT  = 2048;       // int[196] bucket edge count
static const size_t OFF_WT   = 3072;       // ushort[128*128] bf16 W^T [n][k]
static const size_t OFF_H    = 35840;      // int[196*256] per-(bucket,block) counts
static const size_t OFF_BB   = 236544;     // int[196*256] absolute scatter bases
static const size_t OFF_DEG  = 437248;     // int[50000]
static const size_t OFF_OFFS = 637952;     // int[50000]
static const size_t OFF_INV  = 838656;     // float[50000]
static const size_t OFF_REC  = 1039360;    // uint[800000] (src | dstLocal<<16)
static const size_t OFF_CSR  = 4239360;    // ushort[800000]
static const size_t OFF_XWB  = 5839360;    // ushort[50000*128] bf16
// total: 18,639,360 bytes

#define BM 64
#define NB_GEMM ((N_NODES + BM - 1) / BM)   // 782

__device__ __forceinline__ unsigned short f2bf(float f) {
    unsigned int u = __float_as_uint(f);
    unsigned int r = (u + 0x7fffu + ((u >> 16) & 1u)) >> 16;   // RNE
    return (unsigned short)r;
}
__device__ __forceinline__ float bflo(unsigned int u) { return __uint_as_float(u << 16); }
__device__ __forceinline__ float bfhi(unsigned int u) { return __uint_as_float(u & 0xffff0000u); }

// ---- launch 1: pass-A histogram (blocks 0..255) ∥ Wt conversion (256..319) ∥ flag zero (320) ----
__global__ __launch_bounds__(256) void k_pre(const int* __restrict__ dst,
                                             int* __restrict__ H,
                                             const float* __restrict__ W,
                                             unsigned short* __restrict__ Wt,
                                             int* __restrict__ flag) {
    __shared__ unsigned int cnt[256];
    int bid = blockIdx.x, t = threadIdx.x;
    if (bid >= NBLK) {
        if (bid == NBLK + 64) {
            if (t < NBKT) flag[t] = 0;
        } else {
            int idx = (bid - NBLK) * 256 + t;   // 0..16383
            int n = idx >> 7, k = idx & 127;
            Wt[n * D + k] = f2bf(W[k * D + n]);
        }
        return;
    }
    cnt[t] = 0;
    __syncthreads();
    int e0 = bid * EPB;
    for (int i = t; i < EPB; i += 256)
        atomicAdd(&cnt[dst[e0 + i] >> 8], 1u);
    __syncthreads();
    if (t < NBKT) H[t * NBLK + bid] = (int)cnt[t];
}

// ---- launch 2: per-bucket scan over blocks + lookback over buckets ----
__global__ __launch_bounds__(256) void k_pB(const int* __restrict__ H,
                                            int* __restrict__ BB,
                                            int* __restrict__ TOT,
                                            int* __restrict__ flag,
                                            int* __restrict__ BASE) {
    int k = blockIdx.x, t = threadIdx.x;
    int w = t >> 6, l = t & 63;
    int v = H[k * NBLK + t];
    int s = v;
    #pragma unroll
    for (int d = 1; d < 64; d <<= 1) {
        int u = __shfl_up(s, d, 64);
        if (l >= d) s += u;
    }
    __shared__ int wtot[4], woff[4], red[4];
    __shared__ int s_base;
    if (l == 63) wtot[w] = s;
    __syncthreads();
    if (t == 0) {
        woff[0] = 0; woff[1] = wtot[0];
        woff[2] = wtot[0] + wtot[1]; woff[3] = wtot[0] + wtot[1] + wtot[2];
    }
    __syncthreads();
    int excl = s - v + woff[w];
    int T = woff[3] + wtot[3];
    if (t == 0) {
        TOT[k] = T;
        __threadfence();
        atomicExch(&flag[k], 1);
    }
    int pv = 0;
    if (t < k) {
        while (atomicAdd(&flag[t], 0) == 0) { }
    }
    __threadfence();
    if (t < k) pv = atomicAdd(&TOT[t], 0);
    #pragma unroll
    for (int off = 32; off >= 1; off >>= 1) pv += __shfl_down(pv, off, 64);
    if (l == 0) red[w] = pv;
    __syncthreads();
    if (t == 0) {
        s_base = red[0] + red[1] + red[2] + red[3];
        BASE[k] = s_base;
    }
    __syncthreads();
    BB[k * NBLK + t] = s_base + excl;
}

// ---- launch 3: rank-capturing re-histogram + record scatter (bucket-grouped) ----
__global__ __launch_bounds__(512) void k_pC(const int* __restrict__ src,
                                            const int* __restrict__ dst,
                                            const int* __restrict__ BB,
                                            unsigned int* __restrict__ rec) {
    __shared__ unsigned int cnt[200];
    __shared__ int myBB[NBKT];
    int b = blockIdx.x, t = threadIdx.x;
    if (t < 200) cnt[t] = 0;
    if (t < NBKT) myBB[t] = BB[t * NBLK + b];
    __syncthreads();
    int e0 = b * EPB;
    for (int i = t; i < EPB; i += 512) {
        int e = e0 + i;
        int d = dst[e];
        int k = d >> 8;
        unsigned int r = atomicAdd(&cnt[k], 1u);
        rec[myBB[k] + (int)r] = (unsigned int)src[e] | ((unsigned int)(d & 255) << 16);
    }
}

// ---- launch 4: pass D (blocks 0..195) ∥ MFMA GEMM (blocks 196..977) ----
__global__ __launch_bounds__(256) void k_mid(const unsigned int* __restrict__ rec,
                                             const int* __restrict__ BASE,
                                             const int* __restrict__ TOT,
                                             int* __restrict__ deg,
                                             int* __restrict__ offs,
                                             float* __restrict__ inv,
                                             unsigned short* __restrict__ csr,
                                             const float* __restrict__ X,
                                             const unsigned short* __restrict__ Wt,
                                             unsigned short* __restrict__ XWb) {
    __shared__ unsigned short sA[BM * D];    // 16KB (gemm A) / pD scratch
    __shared__ unsigned short sB[D * D];     // 32KB (gemm B)
    __shared__ int wtot[4], woff[4];
    int bid = blockIdx.x;
    int t = threadIdx.x;
    int w = t >> 6, l = t & 63;

    if (bid >= NBKT) {
        // ---------------- GEMM path ----------------
        int r0 = (bid - NBKT) * BM;

        #pragma unroll
        for (int p = 0; p < 8; ++p) {
            int e = p * 2048 + t * 8;
            int n = e >> 7, k = e & 127;
            uint4 v = *(const uint4*)&Wt[e];
            int idx = n * D + (((k >> 3) ^ (n & 7)) << 3);
            *(uint4*)&sB[idx] = v;
        }
        #pragma unroll
        for (int p = 0; p < 8; ++p) {
            int e = p * 1024 + t * 4;
            int r = e >> 7, c = e & 127;
            int row = r0 + r;
            float4 xv = make_float4(0.f, 0.f, 0.f, 0.f);
            if (row < N_NODES) xv = *(const float4*)&X[row * D + c];
            ushort4 bv;
            bv.x = f2bf(xv.x); bv.y = f2bf(xv.y); bv.z = f2bf(xv.z); bv.w = f2bf(xv.w);
            int idx = r * D + (((c >> 3) ^ (r & 7)) << 3) + (c & 7);
            *(ushort4*)&sA[idx] = bv;
        }
        __syncthreads();

        int arow = w * 16 + (l & 15);
        f32x4 acc[8];
        #pragma unroll
        for (int i = 0; i < 8; ++i) acc[i] = (f32x4){0.f, 0.f, 0.f, 0.f};

        #pragma unroll
        for (int kk = 0; kk < 4; ++kk) {
            int g = kk * 4 + (l >> 4);
            bf16x8 a = *(bf16x8*)&sA[arow * D + ((g ^ (arow & 7)) << 3)];
            #pragma unroll
            for (int nt = 0; nt < 8; ++nt) {
                int nrow = nt * 16 + (l & 15);
                bf16x8 b = *(bf16x8*)&sB[nrow * D + ((g ^ (nrow & 7)) << 3)];
                acc[nt] = __builtin_amdgcn_mfma_f32_16x16x32_bf16(a, b, acc[nt], 0, 0, 0);
            }
        }

        #pragma unroll
        for (int nt = 0; nt < 8; ++nt) {
            #pragma unroll
            for (int r = 0; r < 4; ++r) {
                int m = r0 + w * 16 + (l >> 4) * 4 + r;
                if (m < N_NODES) XWb[m * D + nt * 16 + (l & 15)] = f2bf(acc[nt][r]);
            }
        }
        return;
    }

    // ---------------- pass D path (bucket sort -> deg/inv/offs + csr) ----------------
    unsigned int* lcnt = (unsigned int*)sA;       // [256]
    int* off_l = ((int*)sA) + 256;                // [256]
    int k = bid;
    int base = BASE[k], tot = TOT[k];

    lcnt[t] = 0;
    __syncthreads();
    for (int i = t; i < tot; i += 256)
        atomicAdd(&lcnt[rec[base + i] >> 16], 1u);
    __syncthreads();

    int v = (int)lcnt[t];
    int s = v;
    #pragma unroll
    for (int d = 1; d < 64; d <<= 1) {
        int u = __shfl_up(s, d, 64);
        if (l >= d) s += u;
    }
    if (l == 63) wtot[w] = s;
    __syncthreads();
    if (t == 0) {
        woff[0] = 0; woff[1] = wtot[0];
        woff[2] = wtot[0] + wtot[1]; woff[3] = wtot[0] + wtot[1] + wtot[2];
    }
    __syncthreads();
    int excl = s - v + woff[w];
    off_l[t] = excl;
    int node = k * 256 + t;
    if (node < N_NODES) {
        deg[node] = v;
        inv[node] = rsqrtf((float)v + 1.0f);
        offs[node] = base + excl;
    }
    __syncthreads();
    lcnt[t] = 0;
    __syncthreads();
    for (int i = t; i < tot; i += 256) {
        unsigned int rc = rec[base + i];
        int dl = rc >> 16;
        unsigned int r = atomicAdd(&lcnt[dl], 1u);
        csr[base + off_l[dl] + (int)r] = (unsigned short)(rc & 0xFFFFu);
    }
}

// ---- launch 5: aggregate (bf16 gather, f32 out), 4-deep gather pipeline ----
__global__ __launch_bounds__(256) void k_agg(const unsigned short* __restrict__ XWb,
                                             const unsigned short* __restrict__ csr,
                                             const int* __restrict__ offs,
                                             const int* __restrict__ deg,
                                             const float* __restrict__ inv,
                                             float* __restrict__ out) {
    int node = blockIdx.x * 4 + (threadIdx.x >> 6);
    if (node >= N_NODES) return;
    int l = threadIdx.x & 63;
    int eg = l >> 4;
    int cl = l & 15;

    int start = offs[node];
    int cnt = deg[node];
    float invd = inv[node];

    float acc[8];
    #pragma unroll
    for (int j = 0; j < 8; ++j) acc[j] = 0.f;

    if (eg == 0) {
        float sl = invd * invd;
        uint4 v = *(const uint4*)&XWb[node * D + cl * 8];
        acc[0] += sl * bflo(v.x); acc[1] += sl * bfhi(v.x);
        acc[2] += sl * bflo(v.y); acc[3] += sl * bfhi(v.y);
        acc[4] += sl * bflo(v.z); acc[5] += sl * bfhi(v.z);
        acc[6] += sl * bflo(v.w); acc[7] += sl * bfhi(v.w);
    }

    for (int e = eg; e < cnt; e += 16) {
        int s[4];
        #pragma unroll
        for (int u = 0; u < 4; ++u) {
            int ee = e + u * 4;
            s[u] = (ee < cnt) ? (int)csr[start + ee] : -1;
        }
        uint4 v[4];
        float nn[4];
        #pragma unroll
        for (int u = 0; u < 4; ++u) {
            int si = (s[u] >= 0) ? s[u] : s[0];
            v[u] = *(const uint4*)&XWb[si * D + cl * 8];
            nn[u] = (s[u] >= 0) ? invd * inv[si] : 0.f;
        }
        #pragma unroll
        for (int u = 0; u < 4; ++u) {
            float n = nn[u];
            acc[0] += n * bflo(v[u].x); acc[1] += n * bfhi(v[u].x);
            acc[2] += n * bflo(v[u].y); acc[3] += n * bfhi(v[u].y);
            acc[4] += n * bflo(v[u].z); acc[5] += n * bfhi(v[u].z);
            acc[6] += n * bflo(v[u].w); acc[7] += n * bfhi(v[u].w);
        }
    }

    #pragma unroll
    for (int j = 0; j < 8; ++j) {
        acc[j] += __shfl_xor(acc[j], 16, 64);
        acc[j] += __shfl_xor(acc[j], 32, 64);
    }

    if (l < 16) {
        float4 v0 = make_float4(acc[0], acc[1], acc[2], acc[3]);
        float4 v1 = make_float4(acc[4], acc[5], acc[6], acc[7]);
        *(float4*)&out[node * D + cl * 8] = v0;
        *(float4*)&out[node * D + cl * 8 + 4] = v1;
    }
}

extern "C" void kernel_launch(void* const* d_in, const int* in_sizes, int n_in,
                              void* d_out, int out_size, void* d_ws, size_t ws_size,
                              hipStream_t stream) {
    const float* X = (const float*)d_in[0];
    const float* W = (const float*)d_in[1];
    const int* esrc = (const int*)d_in[2];
    const int* edst = (const int*)d_in[3];
    float* out = (float*)d_out;

    char* ws = (char*)d_ws;
    int* flag = (int*)(ws + OFF_FLAG);
    int* BASE = (int*)(ws + OFF_BASE);
    int* TOT = (int*)(ws + OFF_TOT);
    unsigned short* Wt = (unsigned short*)(ws + OFF_WT);
    int* H = (int*)(ws + OFF_H);
    int* BB = (int*)(ws + OFF_BB);
    int* deg = (int*)(ws + OFF_DEG);
    int* offs = (int*)(ws + OFF_OFFS);
    float* inv = (float*)(ws + OFF_INV);
    unsigned int* rec = (unsigned int*)(ws + OFF_REC);
    unsigned short* csr = (unsigned short*)(ws + OFF_CSR);
    unsigned short* XWb = (unsigned short*)(ws + OFF_XWB);

    k_pre<<<NBLK + 65, 256, 0, stream>>>(edst, H, W, Wt, flag);
    k_pB<<<NBKT, 256, 0, stream>>>(H, BB, TOT, flag, BASE);
    k_pC<<<NBLK, 512, 0, stream>>>(esrc, edst, BB, rec);
    k_mid<<<NBKT + NB_GEMM, 256, 0, stream>>>(rec, BASE, TOT, deg, offs, inv, csr,
                                              X, Wt, XWb);
    k_agg<<<(N_NODES + 3) / 4, 256, 0, stream>>>(XWb, csr, offs, deg, inv, out);
}

// Round 13
// 65.905 us; speedup vs baseline: 2.6818x; 1.3255x over previous
//
#include <hip/hip_runtime.h>

#define N_NODES 50000
#define N_EDGES 800000
#define D 128

#define NBLK 256                  // partition blocks
#define EPB (N_EDGES / NBLK)      // 3125 edges per block
#define NBKT 196                  // coarse buckets of 256 nodes
#define CAP 6144                  // fixed slots per bucket (mean 4096, +32 sigma)

typedef __attribute__((ext_vector_type(8))) short bf16x8;
typedef __attribute__((ext_vector_type(4))) float f32x4;

// ---------------- workspace layout (bytes) ----------------
static const size_t OFF_TOT  = 0;          // int[196] bucket edge count
static const size_t OFF_WT   = 1024;       // ushort[128*128] bf16 W^T [n][k]
static const size_t OFF_H    = 33792;      // int[196*256] per-(bucket,block) counts
static const size_t OFF_BB   = 234496;     // int[196*256] rel scatter bases
static const size_t OFF_DEG  = 435200;     // int[50000]
static const size_t OFF_OFFS = 635200;     // int[50000]
static const size_t OFF_INV  = 835200;     // float[50000]
static const size_t OFF_REC  = 1035264;    // uint[196*6144] (src | dstLocal<<16)
static const size_t OFF_CSR  = 5852160;    // ushort[196*6144]
static const size_t OFF_XWB  = 8260608;    // ushort[50000*128] bf16
// total: 21,060,608 bytes

#define BM 64
#define NB_GEMM ((N_NODES + BM - 1) / BM)   // 782

__device__ __forceinline__ unsigned short f2bf(float f) {
    unsigned int u = __float_as_uint(f);
    unsigned int r = (u + 0x7fffu + ((u >> 16) & 1u)) >> 16;   // RNE
    return (unsigned short)r;
}
__device__ __forceinline__ float bflo(unsigned int u) { return __uint_as_float(u << 16); }
__device__ __forceinline__ float bfhi(unsigned int u) { return __uint_as_float(u & 0xffff0000u); }

// ---- launch 1: pass-A histogram (blocks 0..255) ∥ Wt conversion (256..319) ----
__global__ __launch_bounds__(256) void k_pre(const int* __restrict__ dst,
                                             int* __restrict__ H,
                                             const float* __restrict__ W,
                                             unsigned short* __restrict__ Wt) {
    __shared__ unsigned int cnt[256];
    int bid = blockIdx.x, t = threadIdx.x;
    if (bid >= NBLK) {
        int idx = (bid - NBLK) * 256 + t;   // 0..16383
        int n = idx >> 7, k = idx & 127;
        Wt[n * D + k] = f2bf(W[k * D + n]);
        return;
    }
    cnt[t] = 0;
    __syncthreads();
    int e0 = bid * EPB;
    for (int i = t; i < EPB; i += 256)
        atomicAdd(&cnt[dst[e0 + i] >> 8], 1u);
    __syncthreads();
    if (t < NBKT) H[t * NBLK + bid] = (int)cnt[t];
}

// ---- launch 2: per-bucket scan over blocks (fully independent, no lookback) ----
__global__ __launch_bounds__(256) void k_pB(const int* __restrict__ H,
                                            int* __restrict__ BB,
                                            int* __restrict__ TOT) {
    int k = blockIdx.x, t = threadIdx.x;
    int w = t >> 6, l = t & 63;
    int v = H[k * NBLK + t];
    int s = v;
    #pragma unroll
    for (int d = 1; d < 64; d <<= 1) {
        int u = __shfl_up(s, d, 64);
        if (l >= d) s += u;
    }
    __shared__ int wtot[4], woff[4];
    if (l == 63) wtot[w] = s;
    __syncthreads();
    if (t == 0) {
        woff[0] = 0; woff[1] = wtot[0];
        woff[2] = wtot[0] + wtot[1]; woff[3] = wtot[0] + wtot[1] + wtot[2];
    }
    __syncthreads();
    int excl = s - v + woff[w];
    BB[k * NBLK + t] = excl;
    if (t == 255) TOT[k] = excl + v;
}

// ---- launch 3: rank-capturing re-histogram + record scatter (bucket-grouped) ----
__global__ __launch_bounds__(512) void k_pC(const int* __restrict__ src,
                                            const int* __restrict__ dst,
                                            const int* __restrict__ BB,
                                            unsigned int* __restrict__ rec) {
    __shared__ unsigned int cnt[200];
    __shared__ int myBB[NBKT];
    int b = blockIdx.x, t = threadIdx.x;
    if (t < 200) cnt[t] = 0;
    if (t < NBKT) myBB[t] = t * CAP + BB[t * NBLK + b];
    __syncthreads();
    int e0 = b * EPB;
    for (int i = t; i < EPB; i += 512) {
        int e = e0 + i;
        int d = dst[e];
        int k = d >> 8;
        unsigned int r = atomicAdd(&cnt[k], 1u);
        rec[myBB[k] + (int)r] = (unsigned int)src[e] | ((unsigned int)(d & 255) << 16);
    }
}

// ---- launch 4: pass D (blocks 0..195) ∥ MFMA GEMM (blocks 196..977) ----
__global__ __launch_bounds__(256) void k_mid(const unsigned int* __restrict__ rec,
                                             const int* __restrict__ TOT,
                                             int* __restrict__ deg,
                                             int* __restrict__ offs,
                                             float* __restrict__ inv,
                                             unsigned short* __restrict__ csr,
                                             const float* __restrict__ X,
                                             const unsigned short* __restrict__ Wt,
                                             unsigned short* __restrict__ XWb) {
    __shared__ unsigned short sA[BM * D];    // 16KB (gemm A) / pD scratch
    __shared__ unsigned short sB[D * D];     // 32KB (gemm B)
    __shared__ int wtot[4], woff[4];
    int bid = blockIdx.x;
    int t = threadIdx.x;
    int w = t >> 6, l = t & 63;

    if (bid >= NBKT) {
        // ---------------- GEMM path ----------------
        int r0 = (bid - NBKT) * BM;

        #pragma unroll
        for (int p = 0; p < 8; ++p) {
            int e = p * 2048 + t * 8;
            int n = e >> 7, k = e & 127;
            uint4 v = *(const uint4*)&Wt[e];
            int idx = n * D + (((k >> 3) ^ (n & 7)) << 3);
            *(uint4*)&sB[idx] = v;
        }
        #pragma unroll
        for (int p = 0; p < 8; ++p) {
            int e = p * 1024 + t * 4;
            int r = e >> 7, c = e & 127;
            int row = r0 + r;
            float4 xv = make_float4(0.f, 0.f, 0.f, 0.f);
            if (row < N_NODES) xv = *(const float4*)&X[row * D + c];
            ushort4 bv;
            bv.x = f2bf(xv.x); bv.y = f2bf(xv.y); bv.z = f2bf(xv.z); bv.w = f2bf(xv.w);
            int idx = r * D + (((c >> 3) ^ (r & 7)) << 3) + (c & 7);
            *(ushort4*)&sA[idx] = bv;
        }
        __syncthreads();

        int arow = w * 16 + (l & 15);
        f32x4 acc[8];
        #pragma unroll
        for (int i = 0; i < 8; ++i) acc[i] = (f32x4){0.f, 0.f, 0.f, 0.f};

        #pragma unroll
        for (int kk = 0; kk < 4; ++kk) {
            int g = kk * 4 + (l >> 4);
            bf16x8 a = *(bf16x8*)&sA[arow * D + ((g ^ (arow & 7)) << 3)];
            #pragma unroll
            for (int nt = 0; nt < 8; ++nt) {
                int nrow = nt * 16 + (l & 15);
                bf16x8 b = *(bf16x8*)&sB[nrow * D + ((g ^ (nrow & 7)) << 3)];
                acc[nt] = __builtin_amdgcn_mfma_f32_16x16x32_bf16(a, b, acc[nt], 0, 0, 0);
            }
        }

        #pragma unroll
        for (int nt = 0; nt < 8; ++nt) {
            #pragma unroll
            for (int r = 0; r < 4; ++r) {
                int m = r0 + w * 16 + (l >> 4) * 4 + r;
                if (m < N_NODES) XWb[m * D + nt * 16 + (l & 15)] = f2bf(acc[nt][r]);
            }
        }
        return;
    }

    // ---------------- pass D path (bucket sort -> deg/inv/offs + csr) ----------------
    unsigned int* lcnt = (unsigned int*)sA;       // [256]
    int* off_l = ((int*)sA) + 256;                // [256]
    int k = bid;
    int base = k * CAP;
    int tot = TOT[k];

    lcnt[t] = 0;
    __syncthreads();
    for (int i = t; i < tot; i += 256)
        atomicAdd(&lcnt[rec[base + i] >> 16], 1u);
    __syncthreads();

    int v = (int)lcnt[t];
    int s = v;
    #pragma unroll
    for (int d = 1; d < 64; d <<= 1) {
        int u = __shfl_up(s, d, 64);
        if (l >= d) s += u;
    }
    if (l == 63) wtot[w] = s;
    __syncthreads();
    if (t == 0) {
        woff[0] = 0; woff[1] = wtot[0];
        woff[2] = wtot[0] + wtot[1]; woff[3] = wtot[0] + wtot[1] + wtot[2];
    }
    __syncthreads();
    int excl = s - v + woff[w];
    off_l[t] = excl;
    int node = k * 256 + t;
    if (node < N_NODES) {
        deg[node] = v;
        inv[node] = rsqrtf((float)v + 1.0f);
        offs[node] = base + excl;
    }
    __syncthreads();
    lcnt[t] = 0;
    __syncthreads();
    for (int i = t; i < tot; i += 256) {
        unsigned int rc = rec[base + i];
        int dl = rc >> 16;
        unsigned int r = atomicAdd(&lcnt[dl], 1u);
        csr[base + off_l[dl] + (int)r] = (unsigned short)(rc & 0xFFFFu);
    }
}

// ---- launch 5: aggregate (bf16 gather, f32 out), 4-deep gather pipeline ----
__global__ __launch_bounds__(256) void k_agg(const unsigned short* __restrict__ XWb,
                                             const unsigned short* __restrict__ csr,
                                             const int* __restrict__ offs,
                                             const int* __restrict__ deg,
                                             const float* __restrict__ inv,
                                             float* __restrict__ out) {
    int node = blockIdx.x * 4 + (threadIdx.x >> 6);
    if (node >= N_NODES) return;
    int l = threadIdx.x & 63;
    int eg = l >> 4;
    int cl = l & 15;

    int start = offs[node];
    int cnt = deg[node];
    float invd = inv[node];

    float acc[8];
    #pragma unroll
    for (int j = 0; j < 8; ++j) acc[j] = 0.f;

    if (eg == 0) {
        float sl = invd * invd;
        uint4 v = *(const uint4*)&XWb[node * D + cl * 8];
        acc[0] += sl * bflo(v.x); acc[1] += sl * bfhi(v.x);
        acc[2] += sl * bflo(v.y); acc[3] += sl * bfhi(v.y);
        acc[4] += sl * bflo(v.z); acc[5] += sl * bfhi(v.z);
        acc[6] += sl * bflo(v.w); acc[7] += sl * bfhi(v.w);
    }

    for (int e = eg; e < cnt; e += 16) {
        int s[4];
        #pragma unroll
        for (int u = 0; u < 4; ++u) {
            int ee = e + u * 4;
            s[u] = (ee < cnt) ? (int)csr[start + ee] : -1;
        }
        uint4 v[4];
        float nn[4];
        #pragma unroll
        for (int u = 0; u < 4; ++u) {
            int si = (s[u] >= 0) ? s[u] : s[0];
            v[u] = *(const uint4*)&XWb[si * D + cl * 8];
            nn[u] = (s[u] >= 0) ? invd * inv[si] : 0.f;
        }
        #pragma unroll
        for (int u = 0; u < 4; ++u) {
            float n = nn[u];
            acc[0] += n * bflo(v[u].x); acc[1] += n * bfhi(v[u].x);
            acc[2] += n * bflo(v[u].y); acc[3] += n * bfhi(v[u].y);
            acc[4] += n * bflo(v[u].z); acc[5] += n * bfhi(v[u].z);
            acc[6] += n * bflo(v[u].w); acc[7] += n * bfhi(v[u].w);
        }
    }

    #pragma unroll
    for (int j = 0; j < 8; ++j) {
        acc[j] += __shfl_xor(acc[j], 16, 64);
        acc[j] += __shfl_xor(acc[j], 32, 64);
    }

    if (l < 16) {
        float4 v0 = make_float4(acc[0], acc[1], acc[2], acc[3]);
        float4 v1 = make_float4(acc[4], acc[5], acc[6], acc[7]);
        *(float4*)&out[node * D + cl * 8] = v0;
        *(float4*)&out[node * D + cl * 8 + 4] = v1;
    }
}

extern "C" void kernel_launch(void* const* d_in, const int* in_sizes, int n_in,
                              void* d_out, int out_size, void* d_ws, size_t ws_size,
                              hipStream_t stream) {
    const float* X = (const float*)d_in[0];
    const float* W = (const float*)d_in[1];
    const int* esrc = (const int*)d_in[2];
    const int* edst = (const int*)d_in[3];
    float* out = (float*)d_out;

    char* ws = (char*)d_ws;
    int* TOT = (int*)(ws + OFF_TOT);
    unsigned short* Wt = (unsigned short*)(ws + OFF_WT);
    int* H = (int*)(ws + OFF_H);
    int* BB = (int*)(ws + OFF_BB);
    int* deg = (int*)(ws + OFF_DEG);
    int* offs = (int*)(ws + OFF_OFFS);
    float* inv = (float*)(ws + OFF_INV);
    unsigned int* rec = (unsigned int*)(ws + OFF_REC);
    unsigned short* csr = (unsigned short*)(ws + OFF_CSR);
    unsigned short* XWb = (unsigned short*)(ws + OFF_XWB);

    k_pre<<<NBLK + 64, 256, 0, stream>>>(edst, H, W, Wt);
    k_pB<<<NBKT, 256, 0, stream>>>(H, BB, TOT);
    k_pC<<<NBLK, 512, 0, stream>>>(esrc, edst, BB, rec);
    k_mid<<<NBKT + NB_GEMM, 256, 0, stream>>>(rec, TOT, deg, offs, inv, csr,
                                              X, Wt, XWb);
    k_agg<<<(N_NODES + 3) / 4, 256, 0, stream>>>(XWb, csr, offs, deg, inv, out);
}